// Round 1
// baseline (518.589 us; speedup 1.0000x reference)
//
#include <hip/hip_runtime.h>

#define Ff 16
#define Kk 8
#define SIZEk 64
#define PDd 256
#define EDd 768
#define Nn 197
#define BZz 512          // B*F
#define ED4 192          // 768/4
#define PD4 64           // 256/4

// ---------------- Kernel 1: frame mean  x[B,F,N,ED] -> xf[BZ,ED] ----------------
// Also zeroes the two scalar accumulators (diff_sum, ksim_sum).
__global__ __launch_bounds__(192) void k_mean(const float4* __restrict__ x,
                                              float* __restrict__ xf,
                                              float* __restrict__ acc) {
    int bf = blockIdx.x;
    int t  = threadIdx.x;            // 0..191 (one float4 column each)
    if (bf == 0 && t < 2) acc[t] = 0.0f;

    const float4* base = x + (size_t)bf * Nn * ED4;
    float4 s = make_float4(0.f, 0.f, 0.f, 0.f);
    int n = 0;
    for (; n + 4 <= Nn; n += 4) {
        float4 a = base[(n + 0) * ED4 + t];
        float4 b = base[(n + 1) * ED4 + t];
        float4 c = base[(n + 2) * ED4 + t];
        float4 d = base[(n + 3) * ED4 + t];
        s.x += a.x + b.x + c.x + d.x;
        s.y += a.y + b.y + c.y + d.y;
        s.z += a.z + b.z + c.z + d.z;
        s.w += a.w + b.w + c.w + d.w;
    }
    for (; n < Nn; n++) {
        float4 a = base[n * ED4 + t];
        s.x += a.x; s.y += a.y; s.z += a.z; s.w += a.w;
    }
    const float inv = 1.0f / (float)Nn;
    s.x *= inv; s.y *= inv; s.z *= inv; s.w *= inv;
    ((float4*)xf)[(size_t)bf * ED4 + t] = s;
}

// ---------------- Kernel 2: query = xf @ W_in^T, then row L2-norm -> q[BZ,PD] ---
// 4 bf-rows per block so each W_in read is reused 4x.
__global__ __launch_bounds__(256) void k_query(const float* __restrict__ xf,
                                               const float* __restrict__ Win,
                                               float* __restrict__ q) {
    __shared__ float xs[4][EDd];
    __shared__ float red[4][4];
    __shared__ float norms[4];
    int t   = threadIdx.x;           // 0..255 == output p
    int bf0 = blockIdx.x * 4;

    for (int i = t; i < 4 * EDd; i += 256) ((float*)xs)[i] = xf[(size_t)bf0 * EDd + i];
    __syncthreads();

    const float4* w = (const float4*)Win + (size_t)t * ED4;
    float d0 = 0.f, d1 = 0.f, d2 = 0.f, d3 = 0.f;
    for (int i = 0; i < ED4; i++) {
        float4 wv = w[i];
        float4 x0 = ((const float4*)xs[0])[i];
        float4 x1 = ((const float4*)xs[1])[i];
        float4 x2 = ((const float4*)xs[2])[i];
        float4 x3 = ((const float4*)xs[3])[i];
        d0 += wv.x * x0.x + wv.y * x0.y + wv.z * x0.z + wv.w * x0.w;
        d1 += wv.x * x1.x + wv.y * x1.y + wv.z * x1.z + wv.w * x1.w;
        d2 += wv.x * x2.x + wv.y * x2.y + wv.z * x2.z + wv.w * x2.w;
        d3 += wv.x * x3.x + wv.y * x3.y + wv.z * x3.z + wv.w * x3.w;
    }
    float s0 = d0 * d0, s1 = d1 * d1, s2 = d2 * d2, s3 = d3 * d3;
    for (int o = 32; o > 0; o >>= 1) {
        s0 += __shfl_down(s0, o);
        s1 += __shfl_down(s1, o);
        s2 += __shfl_down(s2, o);
        s3 += __shfl_down(s3, o);
    }
    int wid = t >> 6;
    if ((t & 63) == 0) { red[0][wid] = s0; red[1][wid] = s1; red[2][wid] = s2; red[3][wid] = s3; }
    __syncthreads();
    if (t < 4) {
        float ss = red[t][0] + red[t][1] + red[t][2] + red[t][3];
        norms[t] = fmaxf(sqrtf(ss), 1e-12f);
    }
    __syncthreads();
    q[(size_t)(bf0 + 0) * PDd + t] = d0 / norms[0];
    q[(size_t)(bf0 + 1) * PDd + t] = d1 / norms[1];
    q[(size_t)(bf0 + 2) * PDd + t] = d2 / norms[2];
    q[(size_t)(bf0 + 3) * PDd + t] = d3 / norms[3];
}

// ---------------- Kernel 3: keys = l2norm(pv) ; KW = keys @ W_out^T [64,768] ----
__global__ __launch_bounds__(256) void k_keys(const float* __restrict__ pv,
                                              const float* __restrict__ Wout,
                                              float* __restrict__ keys,
                                              float* __restrict__ KW) {
    __shared__ float ks[PDd];
    __shared__ float red[4];
    __shared__ float s_norm;
    int s = blockIdx.x, t = threadIdx.x;     // t == d (0..255)
    float v  = pv[(size_t)s * PDd + t];
    float sq = v * v;
    for (int o = 32; o > 0; o >>= 1) sq += __shfl_down(sq, o);
    if ((t & 63) == 0) red[t >> 6] = sq;
    __syncthreads();
    if (t == 0) s_norm = fmaxf(sqrtf(red[0] + red[1] + red[2] + red[3]), 1e-12f);
    __syncthreads();
    float kv = v / s_norm;
    ks[t] = kv;
    keys[(size_t)s * PDd + t] = kv;
    __syncthreads();

    for (int e = t; e < EDd; e += 256) {
        const float4* w  = (const float4*)(Wout + (size_t)e * PDd);
        const float4* k4 = (const float4*)ks;
        float d = 0.f;
        for (int i = 0; i < PD4; i++) {
            float4 wv = w[i]; float4 kvv = k4[i];
            d += wv.x * kvv.x + wv.y * kvv.y + wv.z * kvv.z + wv.w * kvv.w;
        }
        KW[(size_t)s * EDd + e] = d;
    }
}

// ---------------- Kernel 4: ksim_sum = sum |keys@keys^T - I| ---------------------
__global__ __launch_bounds__(64) void k_ksim(const float* __restrict__ keys,
                                             float* __restrict__ acc) {
    int i = blockIdx.x, j = threadIdx.x;
    const float4* a = (const float4*)(keys + (size_t)i * PDd);
    const float4* b = (const float4*)(keys + (size_t)j * PDd);
    float d = 0.f;
    for (int c = 0; c < PD4; c++) {
        float4 av = a[c], bv = b[c];
        d += av.x * bv.x + av.y * bv.y + av.z * bv.z + av.w * bv.w;
    }
    float v = fabsf(d - (i == j ? 1.0f : 0.0f));
    for (int o = 32; o > 0; o >>= 1) v += __shfl_down(v, o);
    if (j == 0) atomicAdd(acc + 1, v);
}

// ---------------- Kernel 5: sim, top-8, recon/diff, gather-write out -------------
__global__ __launch_bounds__(256) void k_route(const float* __restrict__ q,
                                               const float* __restrict__ keys,
                                               const float* __restrict__ KW,
                                               float* __restrict__ out,
                                               float* __restrict__ acc) {
    __shared__ float qs[PDd];
    __shared__ int   s_idx[Kk];
    __shared__ float s_sim[Kk];
    __shared__ float red[4];
    int bz = blockIdx.x, t = threadIdx.x;
    qs[t] = q[(size_t)bz * PDd + t];
    __syncthreads();

    if (t < SIZEk) {                 // exactly wave 0
        const float4* kr = (const float4*)(keys + (size_t)t * PDd);
        const float4* qr = (const float4*)qs;
        float d = 0.f;
        for (int c = 0; c < PD4; c++) {
            float4 a = kr[c], b = qr[c];
            d += a.x * b.x + a.y * b.y + a.z * b.z + a.w * b.w;
        }
        float v = d;
        for (int k = 0; k < Kk; k++) {
            float mv = v; int mi = t;
            for (int o = 32; o > 0; o >>= 1) {
                float ov = __shfl_xor(mv, o);
                int   oi = __shfl_xor(mi, o);
                if (ov > mv || (ov == mv && oi < mi)) { mv = ov; mi = oi; }
            }
            if (t == 0) { s_idx[k] = mi; s_sim[k] = mv; }
            if (t == mi) v = -3e38f;   // remove winner (tie -> lowest index, like lax.top_k)
        }
    }
    __syncthreads();

    // recon + diff  (thread t == d)
    float r = 0.f;
    for (int k = 0; k < Kk; k++) r += s_sim[k] * keys[(size_t)s_idx[k] * PDd + t];
    float e  = r - qs[t];
    float sq = e * e;
    for (int o = 32; o > 0; o >>= 1) sq += __shfl_down(sq, o);
    if ((t & 63) == 0) red[t >> 6] = sq;
    __syncthreads();
    if (t == 0) atomicAdd(acc, red[0] + red[1] + red[2] + red[3]);

    // out_prompts rows: out row index = bz*K + k, each row = KW[idx[k], :]
    float4* orow = (float4*)out + (size_t)bz * Kk * ED4;
    for (int i = t; i < Kk * ED4; i += 256) {
        int k  = i / ED4;
        int e4 = i - k * ED4;
        orow[i] = ((const float4*)(KW + (size_t)s_idx[k] * EDd))[e4];
    }
}

// ---------------- Kernel 6: ps_loss ---------------------------------------------
__global__ void k_final(const float* __restrict__ acc, float* __restrict__ out) {
    // ps = diff_sum/BZ + ksim_sum/BZ ; ps_loss = ps * F
    out[(size_t)32 * 128 * EDd] = (acc[0] + acc[1]) * ((float)Ff / (float)BZz);
}

extern "C" void kernel_launch(void* const* d_in, const int* in_sizes, int n_in,
                              void* d_out, int out_size, void* d_ws, size_t ws_size,
                              hipStream_t stream) {
    const float* x    = (const float*)d_in[0];   // [32, 16*197, 768]
    const float* Win  = (const float*)d_in[1];   // [256, 768]
    const float* Wout = (const float*)d_in[2];   // [768, 256]
    const float* pv   = (const float*)d_in[3];   // [64, 1, 256]
    float* out = (float*)d_out;                  // [32,128,768] ++ [1]
    float* ws  = (float*)d_ws;

    float* xf   = ws;                 // 512*768   = 393216
    float* q    = ws + 393216;        // 512*256   = 131072
    float* keys = ws + 524288;        // 64*256    = 16384
    float* KW   = ws + 540672;        // 64*768    = 49152
    float* acc  = ws + 589824;        // [0]=diff_sum, [1]=ksim_sum

    k_mean <<<BZz, 192, 0, stream>>>((const float4*)x, xf, acc);
    k_query<<<BZz / 4, 256, 0, stream>>>(xf, Win, q);
    k_keys <<<SIZEk, 256, 0, stream>>>(pv, Wout, keys, KW);
    k_ksim <<<SIZEk, 64, 0, stream>>>(keys, acc);
    k_route<<<BZz, 256, 0, stream>>>(q, keys, KW, out, acc);
    k_final<<<1, 1, 0, stream>>>(acc, out);
}

// Round 2
// 514.138 us; speedup vs baseline: 1.0087x; 1.0087x over previous
//
#include <hip/hip_runtime.h>

#define Ff 16
#define Kk 8
#define SIZEk 64
#define PDd 256
#define EDd 768
#define Nn 197
#define BZz 512          // B*F
#define ED4 192          // 768/4
#define PD4 64           // 256/4
#define OUT_LOSS ((size_t)32 * 128 * EDd)   // 3145728: ps_loss slot in d_out
#define LOSS_SCALE (1.0f / 32.0f)           // F/BZ = 16/512

// ---------------- Kernel 1: frame mean  x[B,F,N,ED] -> xf[BZ,ED] ----------------
// Also zeroes the ps_loss accumulator in d_out (stream order guarantees this
// precedes the route kernel's atomicAdds on every graph replay).
__global__ __launch_bounds__(192) void k_mean(const float4* __restrict__ x,
                                              float* __restrict__ xf,
                                              float* __restrict__ out) {
    int bf = blockIdx.x;
    int t  = threadIdx.x;            // 0..191 (one float4 column each)
    if (bf == 0 && t == 0) out[OUT_LOSS] = 0.0f;

    const float4* base = x + (size_t)bf * Nn * ED4;
    float4 s = make_float4(0.f, 0.f, 0.f, 0.f);
    int n = 0;
    for (; n + 4 <= Nn; n += 4) {
        float4 a = base[(n + 0) * ED4 + t];
        float4 b = base[(n + 1) * ED4 + t];
        float4 c = base[(n + 2) * ED4 + t];
        float4 d = base[(n + 3) * ED4 + t];
        s.x += a.x + b.x + c.x + d.x;
        s.y += a.y + b.y + c.y + d.y;
        s.z += a.z + b.z + c.z + d.z;
        s.w += a.w + b.w + c.w + d.w;
    }
    for (; n < Nn; n++) {
        float4 a = base[n * ED4 + t];
        s.x += a.x; s.y += a.y; s.z += a.z; s.w += a.w;
    }
    const float inv = 1.0f / (float)Nn;
    s.x *= inv; s.y *= inv; s.z *= inv; s.w *= inv;
    ((float4*)xf)[(size_t)bf * ED4 + t] = s;
}

// ---------------- Kernel 2: query = xf @ W_in^T, then row L2-norm -> q[BZ,PD] ---
// 4 bf-rows per block so each W_in read is reused 4x (L2-resident, 100 MB total).
__global__ __launch_bounds__(256) void k_query(const float* __restrict__ xf,
                                               const float* __restrict__ Win,
                                               float* __restrict__ q) {
    __shared__ float xs[4][EDd];
    __shared__ float red[4][4];
    __shared__ float norms[4];
    int t   = threadIdx.x;           // 0..255 == output p
    int bf0 = blockIdx.x * 4;

    for (int i = t; i < 4 * EDd; i += 256) ((float*)xs)[i] = xf[(size_t)bf0 * EDd + i];
    __syncthreads();

    const float4* w = (const float4*)Win + (size_t)t * ED4;
    float d0 = 0.f, d1 = 0.f, d2 = 0.f, d3 = 0.f;
    for (int i = 0; i < ED4; i++) {
        float4 wv = w[i];
        float4 x0 = ((const float4*)xs[0])[i];
        float4 x1 = ((const float4*)xs[1])[i];
        float4 x2 = ((const float4*)xs[2])[i];
        float4 x3 = ((const float4*)xs[3])[i];
        d0 += wv.x * x0.x + wv.y * x0.y + wv.z * x0.z + wv.w * x0.w;
        d1 += wv.x * x1.x + wv.y * x1.y + wv.z * x1.z + wv.w * x1.w;
        d2 += wv.x * x2.x + wv.y * x2.y + wv.z * x2.z + wv.w * x2.w;
        d3 += wv.x * x3.x + wv.y * x3.y + wv.z * x3.z + wv.w * x3.w;
    }
    float s0 = d0 * d0, s1 = d1 * d1, s2 = d2 * d2, s3 = d3 * d3;
    for (int o = 32; o > 0; o >>= 1) {
        s0 += __shfl_down(s0, o);
        s1 += __shfl_down(s1, o);
        s2 += __shfl_down(s2, o);
        s3 += __shfl_down(s3, o);
    }
    int wid = t >> 6;
    if ((t & 63) == 0) { red[0][wid] = s0; red[1][wid] = s1; red[2][wid] = s2; red[3][wid] = s3; }
    __syncthreads();
    if (t < 4) {
        float ss = red[t][0] + red[t][1] + red[t][2] + red[t][3];
        norms[t] = fmaxf(sqrtf(ss), 1e-12f);
    }
    __syncthreads();
    q[(size_t)(bf0 + 0) * PDd + t] = d0 / norms[0];
    q[(size_t)(bf0 + 1) * PDd + t] = d1 / norms[1];
    q[(size_t)(bf0 + 2) * PDd + t] = d2 / norms[2];
    q[(size_t)(bf0 + 3) * PDd + t] = d3 / norms[3];
}

// ---------------- Kernel 3: keys = l2norm(pv) ; KW = keys @ W_out^T [64,768] ----
__global__ __launch_bounds__(256) void k_keys(const float* __restrict__ pv,
                                              const float* __restrict__ Wout,
                                              float* __restrict__ keys,
                                              float* __restrict__ KW) {
    __shared__ float ks[PDd];
    __shared__ float red[4];
    __shared__ float s_norm;
    int s = blockIdx.x, t = threadIdx.x;     // t == d (0..255)
    float v  = pv[(size_t)s * PDd + t];
    float sq = v * v;
    for (int o = 32; o > 0; o >>= 1) sq += __shfl_down(sq, o);
    if ((t & 63) == 0) red[t >> 6] = sq;
    __syncthreads();
    if (t == 0) s_norm = fmaxf(sqrtf(red[0] + red[1] + red[2] + red[3]), 1e-12f);
    __syncthreads();
    float kv = v / s_norm;
    ks[t] = kv;
    keys[(size_t)s * PDd + t] = kv;
    __syncthreads();

    for (int e = t; e < EDd; e += 256) {
        const float4* w  = (const float4*)(Wout + (size_t)e * PDd);
        const float4* k4 = (const float4*)ks;
        float d = 0.f;
        for (int i = 0; i < PD4; i++) {
            float4 wv = w[i]; float4 kvv = k4[i];
            d += wv.x * kvv.x + wv.y * kvv.y + wv.z * kvv.z + wv.w * kvv.w;
        }
        KW[(size_t)s * EDd + e] = d;
    }
}

// ---------------- Kernel 4 (fused): route (blocks 0..511) + ksim (512..575) -----
// Both halves only depend on q/keys/KW; loss terms atomicAdd (pre-scaled by
// F/BZ) into out[OUT_LOSS], which k_mean zeroed earlier on the stream.
__global__ __launch_bounds__(256) void k_route(const float* __restrict__ q,
                                               const float* __restrict__ keys,
                                               const float* __restrict__ KW,
                                               float* __restrict__ out) {
    int blk = blockIdx.x, t = threadIdx.x;

    if (blk >= BZz) {
        // ---- ksim row i: sum_j |keys[i].keys[j] - delta_ij| ----
        int i = blk - BZz;
        if (t < SIZEk) {
            const float4* a = (const float4*)(keys + (size_t)i * PDd);
            const float4* b = (const float4*)(keys + (size_t)t * PDd);
            float d = 0.f;
            for (int c = 0; c < PD4; c++) {
                float4 av = a[c], bv = b[c];
                d += av.x * bv.x + av.y * bv.y + av.z * bv.z + av.w * bv.w;
            }
            float v = fabsf(d - (i == t ? 1.0f : 0.0f));
            for (int o = 32; o > 0; o >>= 1) v += __shfl_down(v, o);
            if (t == 0) atomicAdd(out + OUT_LOSS, v * LOSS_SCALE);
        }
        return;
    }

    // ---- routing for query row bz ----
    __shared__ float qs[PDd];
    __shared__ int   s_idx[Kk];
    __shared__ float s_sim[Kk];
    __shared__ float red[4];
    int bz = blk;
    qs[t] = q[(size_t)bz * PDd + t];
    __syncthreads();

    if (t < SIZEk) {                 // exactly wave 0
        const float4* kr = (const float4*)(keys + (size_t)t * PDd);
        const float4* qr = (const float4*)qs;
        float d = 0.f;
        for (int c = 0; c < PD4; c++) {
            float4 a = kr[c], b = qr[c];
            d += a.x * b.x + a.y * b.y + a.z * b.z + a.w * b.w;
        }
        float v = d;
        for (int k = 0; k < Kk; k++) {
            float mv = v; int mi = t;
            for (int o = 32; o > 0; o >>= 1) {
                float ov = __shfl_xor(mv, o);
                int   oi = __shfl_xor(mi, o);
                if (ov > mv || (ov == mv && oi < mi)) { mv = ov; mi = oi; }
            }
            if (t == 0) { s_idx[k] = mi; s_sim[k] = mv; }
            if (t == mi) v = -3e38f;   // remove winner (tie -> lowest index, like lax.top_k)
        }
    }
    __syncthreads();

    // recon + diff  (thread t == d)
    float r = 0.f;
    for (int k = 0; k < Kk; k++) r += s_sim[k] * keys[(size_t)s_idx[k] * PDd + t];
    float e  = r - qs[t];
    float sq = e * e;
    for (int o = 32; o > 0; o >>= 1) sq += __shfl_down(sq, o);
    if ((t & 63) == 0) red[t >> 6] = sq;
    __syncthreads();
    if (t == 0) atomicAdd(out + OUT_LOSS, (red[0] + red[1] + red[2] + red[3]) * LOSS_SCALE);

    // out_prompts rows: out row index = bz*K + k, each row = KW[idx[k], :]
    float4* orow = (float4*)out + (size_t)bz * Kk * ED4;
    for (int i = t; i < Kk * ED4; i += 256) {
        int k  = i / ED4;
        int e4 = i - k * ED4;
        orow[i] = ((const float4*)(KW + (size_t)s_idx[k] * EDd))[e4];
    }
}

extern "C" void kernel_launch(void* const* d_in, const int* in_sizes, int n_in,
                              void* d_out, int out_size, void* d_ws, size_t ws_size,
                              hipStream_t stream) {
    const float* x    = (const float*)d_in[0];   // [32, 16*197, 768]
    const float* Win  = (const float*)d_in[1];   // [256, 768]
    const float* Wout = (const float*)d_in[2];   // [768, 256]
    const float* pv   = (const float*)d_in[3];   // [64, 1, 256]
    float* out = (float*)d_out;                  // [32,128,768] ++ [1]
    float* ws  = (float*)d_ws;

    float* xf   = ws;                 // 512*768   = 393216
    float* q    = ws + 393216;        // 512*256   = 131072
    float* keys = ws + 524288;        // 64*256    = 16384
    float* KW   = ws + 540672;        // 64*768    = 49152

    k_mean <<<BZz, 192, 0, stream>>>((const float4*)x, xf, out);
    k_query<<<BZz / 4, 256, 0, stream>>>(xf, Win, q);
    k_keys <<<SIZEk, 256, 0, stream>>>(pv, Wout, keys, KW);
    k_route<<<BZz + SIZEk, 256, 0, stream>>>(q, keys, KW, out);
}

// Round 3
// 503.710 us; speedup vs baseline: 1.0295x; 1.0207x over previous
//
#include <hip/hip_runtime.h>

#define Ff 16
#define Kk 8
#define SIZEk 64
#define PDd 256
#define EDd 768
#define Nn 197
#define BZz 512          // B*F
#define ED4 192          // 768/4
#define PD4 64           // 256/4
#define OUT_LOSS ((size_t)32 * 128 * EDd)   // 3145728: ps_loss slot in d_out
#define LOSS_SCALE (1.0f / 32.0f)           // F/BZ = 16/512

// ---------------- Kernel 1: keys = l2norm(pv); KW = keys @ W_out^T; zero loss ---
__global__ __launch_bounds__(256) void k_keys(const float* __restrict__ pv,
                                              const float* __restrict__ Wout,
                                              float* __restrict__ keys,
                                              float* __restrict__ KW,
                                              float* __restrict__ out) {
    __shared__ float ks[PDd];
    __shared__ float red[4];
    __shared__ float s_norm;
    int s = blockIdx.x, t = threadIdx.x;     // t == d (0..255)
    if (s == 0 && t == 0) out[OUT_LOSS] = 0.0f;   // kernel completes before fused kernel starts
    float v  = pv[(size_t)s * PDd + t];
    float sq = v * v;
    for (int o = 32; o > 0; o >>= 1) sq += __shfl_down(sq, o);
    if ((t & 63) == 0) red[t >> 6] = sq;
    __syncthreads();
    if (t == 0) s_norm = fmaxf(sqrtf(red[0] + red[1] + red[2] + red[3]), 1e-12f);
    __syncthreads();
    float kv = v / s_norm;
    ks[t] = kv;
    keys[(size_t)s * PDd + t] = kv;
    __syncthreads();

    for (int e = t; e < EDd; e += 256) {
        const float4* w  = (const float4*)(Wout + (size_t)e * PDd);
        const float4* k4 = (const float4*)ks;
        float d = 0.f;
        for (int i = 0; i < PD4; i++) {
            float4 wv = w[i]; float4 kvv = k4[i];
            d += wv.x * kvv.x + wv.y * kvv.y + wv.z * kvv.z + wv.w * kvv.w;
        }
        KW[(size_t)s * EDd + e] = d;
    }
}

// ---------------- Kernel 2 (fused): mean -> query -> top8 -> diff -> gather ------
// blocks 0..511: one bz each, full pipeline (xf and q live only in LDS).
// blocks 512..575: ksim rows. Loss atomicAdds pre-scaled into out[OUT_LOSS].
__global__ __launch_bounds__(256) void k_fused(const float4* __restrict__ x,
                                               const float* __restrict__ Win,
                                               const float* __restrict__ keys,
                                               const float* __restrict__ KW,
                                               float* __restrict__ out) {
    int blk = blockIdx.x, t = threadIdx.x;

    if (blk >= BZz) {
        // ---- ksim row i: sum_j |keys[i].keys[j] - delta_ij| ----
        int i = blk - BZz;
        if (t < SIZEk) {
            const float4* a = (const float4*)(keys + (size_t)i * PDd);
            const float4* b = (const float4*)(keys + (size_t)t * PDd);
            float d = 0.f;
            for (int c = 0; c < PD4; c++) {
                float4 av = a[c], bv = b[c];
                d += av.x * bv.x + av.y * bv.y + av.z * bv.z + av.w * bv.w;
            }
            float v = fabsf(d - (i == t ? 1.0f : 0.0f));
            for (int o = 32; o > 0; o >>= 1) v += __shfl_down(v, o);
            if (t == 0) atomicAdd(out + OUT_LOSS, v * LOSS_SCALE);
        }
        return;
    }

    __shared__ float xs[EDd];        // xf[bz] (as 192 float4)
    __shared__ float qs[PDd];        // normalized query row
    __shared__ int   s_idx[Kk];
    __shared__ float s_sim[Kk];
    __shared__ float red[4];
    int bz = blk;

    // ---- phase 1: frame mean (threads 0..191, one float4 column each) ----
    if (t < ED4) {
        const float4* base = x + (size_t)bz * Nn * ED4;
        float4 s = make_float4(0.f, 0.f, 0.f, 0.f);
        int n = 0;
        for (; n + 8 <= Nn; n += 8) {      // 8 loads in flight per thread
            float4 a0 = base[(n + 0) * ED4 + t];
            float4 a1 = base[(n + 1) * ED4 + t];
            float4 a2 = base[(n + 2) * ED4 + t];
            float4 a3 = base[(n + 3) * ED4 + t];
            float4 a4 = base[(n + 4) * ED4 + t];
            float4 a5 = base[(n + 5) * ED4 + t];
            float4 a6 = base[(n + 6) * ED4 + t];
            float4 a7 = base[(n + 7) * ED4 + t];
            s.x += ((a0.x + a1.x) + (a2.x + a3.x)) + ((a4.x + a5.x) + (a6.x + a7.x));
            s.y += ((a0.y + a1.y) + (a2.y + a3.y)) + ((a4.y + a5.y) + (a6.y + a7.y));
            s.z += ((a0.z + a1.z) + (a2.z + a3.z)) + ((a4.z + a5.z) + (a6.z + a7.z));
            s.w += ((a0.w + a1.w) + (a2.w + a3.w)) + ((a4.w + a5.w) + (a6.w + a7.w));
        }
        for (; n < Nn; n++) {
            float4 a = base[n * ED4 + t];
            s.x += a.x; s.y += a.y; s.z += a.z; s.w += a.w;
        }
        const float inv = 1.0f / (float)Nn;
        s.x *= inv; s.y *= inv; s.z *= inv; s.w *= inv;
        ((float4*)xs)[t] = s;
    }
    __syncthreads();

    // ---- phase 2: query p=t: dot(W_in[t], xf) then block L2-norm ----
    {
        const float4* w  = (const float4*)Win + (size_t)t * ED4;
        const float4* xv = (const float4*)xs;
        float d = 0.f;
        for (int i = 0; i < ED4; i++) {
            float4 wv = w[i], x0 = xv[i];
            d += wv.x * x0.x + wv.y * x0.y + wv.z * x0.z + wv.w * x0.w;
        }
        float sq = d * d;
        for (int o = 32; o > 0; o >>= 1) sq += __shfl_down(sq, o);
        if ((t & 63) == 0) red[t >> 6] = sq;
        __syncthreads();
        float nrm = fmaxf(sqrtf(red[0] + red[1] + red[2] + red[3]), 1e-12f);
        qs[t] = d / nrm;
    }
    __syncthreads();

    // ---- phase 3: sim + top-8 (wave 0) ----
    if (t < SIZEk) {
        const float4* kr = (const float4*)(keys + (size_t)t * PDd);
        const float4* qr = (const float4*)qs;
        float d = 0.f;
        for (int c = 0; c < PD4; c++) {
            float4 a = kr[c], b = qr[c];
            d += a.x * b.x + a.y * b.y + a.z * b.z + a.w * b.w;
        }
        float v = d;
        for (int k = 0; k < Kk; k++) {
            float mv = v; int mi = t;
            for (int o = 32; o > 0; o >>= 1) {
                float ov = __shfl_xor(mv, o);
                int   oi = __shfl_xor(mi, o);
                if (ov > mv || (ov == mv && oi < mi)) { mv = ov; mi = oi; }
            }
            if (t == 0) { s_idx[k] = mi; s_sim[k] = mv; }
            if (t == mi) v = -3e38f;   // remove winner (tie -> lowest index, like lax.top_k)
        }
    }
    __syncthreads();

    // ---- phase 4: recon + diff (thread t == d) ----
    {
        float r = 0.f;
        for (int k = 0; k < Kk; k++) r += s_sim[k] * keys[(size_t)s_idx[k] * PDd + t];
        float e  = r - qs[t];
        float sq = e * e;
        for (int o = 32; o > 0; o >>= 1) sq += __shfl_down(sq, o);
        if ((t & 63) == 0) red[t >> 6] = sq;
        __syncthreads();
        if (t == 0) atomicAdd(out + OUT_LOSS, (red[0] + red[1] + red[2] + red[3]) * LOSS_SCALE);
    }

    // ---- phase 5: out rows bz*K+k = KW[idx[k], :] ----
    float4* orow = (float4*)out + (size_t)bz * Kk * ED4;
    for (int i = t; i < Kk * ED4; i += 256) {
        int k  = i / ED4;
        int e4 = i - k * ED4;
        orow[i] = ((const float4*)(KW + (size_t)s_idx[k] * EDd))[e4];
    }
}

extern "C" void kernel_launch(void* const* d_in, const int* in_sizes, int n_in,
                              void* d_out, int out_size, void* d_ws, size_t ws_size,
                              hipStream_t stream) {
    const float* x    = (const float*)d_in[0];   // [32, 16*197, 768]
    const float* Win  = (const float*)d_in[1];   // [256, 768]
    const float* Wout = (const float*)d_in[2];   // [768, 256]
    const float* pv   = (const float*)d_in[3];   // [64, 1, 256]
    float* out = (float*)d_out;                  // [32,128,768] ++ [1]
    float* ws  = (float*)d_ws;

    float* keys = ws;                 // 64*256 = 16384
    float* KW   = ws + 16384;         // 64*768 = 49152

    k_keys <<<SIZEk, 256, 0, stream>>>(pv, Wout, keys, KW, out);
    k_fused<<<BZz + SIZEk, 256, 0, stream>>>((const float4*)x, Win, keys, KW, out);
}

// Round 4
// 487.336 us; speedup vs baseline: 1.0641x; 1.0336x over previous
//
#include <hip/hip_runtime.h>

#define Ff 16
#define Kk 8
#define SIZEk 64
#define PDd 256
#define EDd 768
#define Nn 197
#define BZz 512          // B*F
#define RB  256          // route blocks (2 bz each)
#define ED4 192          // 768/4
#define PD4 64           // 256/4
#define OUT_LOSS ((size_t)32 * 128 * EDd)   // 3145728: ps_loss slot in d_out
#define LOSS_SCALE (1.0f / 32.0f)           // F/BZ = 16/512

// ---------------- Kernel 1: keys = l2norm(pv); KW = keys @ W_out^T; zero loss ---
__global__ __launch_bounds__(256) void k_keys(const float* __restrict__ pv,
                                              const float* __restrict__ Wout,
                                              float* __restrict__ keys,
                                              float* __restrict__ KW,
                                              float* __restrict__ out) {
    __shared__ float ks[PDd];
    __shared__ float red[4];
    __shared__ float s_norm;
    int s = blockIdx.x, t = threadIdx.x;     // t == d (0..255)
    if (s == 0 && t == 0) out[OUT_LOSS] = 0.0f;   // completes before fused kernel starts
    float v  = pv[(size_t)s * PDd + t];
    float sq = v * v;
    for (int o = 32; o > 0; o >>= 1) sq += __shfl_down(sq, o);
    if ((t & 63) == 0) red[t >> 6] = sq;
    __syncthreads();
    if (t == 0) s_norm = fmaxf(sqrtf(red[0] + red[1] + red[2] + red[3]), 1e-12f);
    __syncthreads();
    float kv = v / s_norm;
    ks[t] = kv;
    keys[(size_t)s * PDd + t] = kv;
    __syncthreads();

    for (int e = t; e < EDd; e += 256) {
        const float4* w  = (const float4*)(Wout + (size_t)e * PDd);
        const float4* k4 = (const float4*)ks;
        float d = 0.f;
        for (int i = 0; i < PD4; i++) {
            float4 wv = w[i]; float4 kvv = k4[i];
            d += wv.x * kvv.x + wv.y * kvv.y + wv.z * kvv.z + wv.w * kvv.w;
        }
        KW[(size_t)s * EDd + e] = d;
    }
}

// ---------------- Kernel 2 (fused): 2 bz per block ------------------------------
// blocks 0..255: bz pair {2b, 2b+1}: mean -> query (W_in read reused 2x) ->
//                top8 (waves 0 & 1 in parallel) -> diff -> KW gather-write.
// blocks 256..319: ksim rows. Loss atomicAdds pre-scaled into out[OUT_LOSS].
__global__ __launch_bounds__(256) void k_fused(const float4* __restrict__ x,
                                               const float* __restrict__ Win,
                                               const float* __restrict__ keys,
                                               const float* __restrict__ KW,
                                               float* __restrict__ out) {
    int blk = blockIdx.x, t = threadIdx.x;

    if (blk >= RB) {
        // ---- ksim row i: sum_j |keys[i].keys[j] - delta_ij| ----
        int i = blk - RB;
        if (t < SIZEk) {
            const float4* a = (const float4*)(keys + (size_t)i * PDd);
            const float4* b = (const float4*)(keys + (size_t)t * PDd);
            float d = 0.f;
            for (int c = 0; c < PD4; c++) {
                float4 av = a[c], bv = b[c];
                d += av.x * bv.x + av.y * bv.y + av.z * bv.z + av.w * bv.w;
            }
            float v = fabsf(d - (i == t ? 1.0f : 0.0f));
            for (int o = 32; o > 0; o >>= 1) v += __shfl_down(v, o);
            if (t == 0) atomicAdd(out + OUT_LOSS, v * LOSS_SCALE);
        }
        return;
    }

    __shared__ float xs[2][EDd];     // xf for both rows (as 192 float4 each)
    __shared__ float qs[2][PDd];     // normalized query rows
    __shared__ int   s_idx[2][Kk];
    __shared__ float s_sim[2][Kk];
    __shared__ float red[2][4];
    int bz0 = blk * 2;

    // ---- phase 1: frame means, both rows (threads 0..191, one f4-column each) --
    if (t < ED4) {
        const float4* b0 = x + (size_t)bz0 * Nn * ED4;
        const float4* b1 = b0 + (size_t)Nn * ED4;
        float4 s0 = make_float4(0.f, 0.f, 0.f, 0.f);
        float4 s1 = make_float4(0.f, 0.f, 0.f, 0.f);
        int n = 0;
        for (; n + 4 <= Nn; n += 4) {      // 8 loads in flight per thread
            float4 a0 = b0[(n + 0) * ED4 + t];
            float4 a1 = b0[(n + 1) * ED4 + t];
            float4 a2 = b0[(n + 2) * ED4 + t];
            float4 a3 = b0[(n + 3) * ED4 + t];
            float4 c0 = b1[(n + 0) * ED4 + t];
            float4 c1 = b1[(n + 1) * ED4 + t];
            float4 c2 = b1[(n + 2) * ED4 + t];
            float4 c3 = b1[(n + 3) * ED4 + t];
            s0.x += (a0.x + a1.x) + (a2.x + a3.x);
            s0.y += (a0.y + a1.y) + (a2.y + a3.y);
            s0.z += (a0.z + a1.z) + (a2.z + a3.z);
            s0.w += (a0.w + a1.w) + (a2.w + a3.w);
            s1.x += (c0.x + c1.x) + (c2.x + c3.x);
            s1.y += (c0.y + c1.y) + (c2.y + c3.y);
            s1.z += (c0.z + c1.z) + (c2.z + c3.z);
            s1.w += (c0.w + c1.w) + (c2.w + c3.w);
        }
        for (; n < Nn; n++) {
            float4 a = b0[n * ED4 + t];
            float4 c = b1[n * ED4 + t];
            s0.x += a.x; s0.y += a.y; s0.z += a.z; s0.w += a.w;
            s1.x += c.x; s1.y += c.y; s1.z += c.z; s1.w += c.w;
        }
        const float inv = 1.0f / (float)Nn;
        s0.x *= inv; s0.y *= inv; s0.z *= inv; s0.w *= inv;
        s1.x *= inv; s1.y *= inv; s1.z *= inv; s1.w *= inv;
        ((float4*)xs[0])[t] = s0;
        ((float4*)xs[1])[t] = s1;
    }
    __syncthreads();

    // ---- phase 2: query p=t for both rows (one W_in read, two dots) ----
    {
        const float4* w  = (const float4*)Win + (size_t)t * ED4;
        const float4* x0 = (const float4*)xs[0];
        const float4* x1 = (const float4*)xs[1];
        float d0 = 0.f, d1 = 0.f;
        for (int i = 0; i < ED4; i++) {
            float4 wv = w[i];
            float4 u0 = x0[i], u1 = x1[i];
            d0 += wv.x * u0.x + wv.y * u0.y + wv.z * u0.z + wv.w * u0.w;
            d1 += wv.x * u1.x + wv.y * u1.y + wv.z * u1.z + wv.w * u1.w;
        }
        float sq0 = d0 * d0, sq1 = d1 * d1;
        for (int o = 32; o > 0; o >>= 1) {
            sq0 += __shfl_down(sq0, o);
            sq1 += __shfl_down(sq1, o);
        }
        if ((t & 63) == 0) { red[0][t >> 6] = sq0; red[1][t >> 6] = sq1; }
        __syncthreads();
        float n0 = fmaxf(sqrtf(red[0][0] + red[0][1] + red[0][2] + red[0][3]), 1e-12f);
        float n1 = fmaxf(sqrtf(red[1][0] + red[1][1] + red[1][2] + red[1][3]), 1e-12f);
        qs[0][t] = d0 / n0;
        qs[1][t] = d1 / n1;
    }
    __syncthreads();

    // ---- phase 3: sim + top-8; wave 0 -> row 0, wave 1 -> row 1 ----
    if (t < 2 * SIZEk) {
        int row  = t >> 6;           // wave id
        int lane = t & 63;
        const float4* kr = (const float4*)(keys + (size_t)lane * PDd);
        const float4* qr = (const float4*)qs[row];
        float d = 0.f;
        for (int c = 0; c < PD4; c++) {
            float4 a = kr[c], b = qr[c];
            d += a.x * b.x + a.y * b.y + a.z * b.z + a.w * b.w;
        }
        float v = d;
        for (int k = 0; k < Kk; k++) {
            float mv = v; int mi = lane;
            for (int o = 32; o > 0; o >>= 1) {
                float ov = __shfl_xor(mv, o);
                int   oi = __shfl_xor(mi, o);
                if (ov > mv || (ov == mv && oi < mi)) { mv = ov; mi = oi; }
            }
            if (lane == 0) { s_idx[row][k] = mi; s_sim[row][k] = mv; }
            if (lane == mi) v = -3e38f;  // remove winner (tie -> lowest idx, like lax.top_k)
        }
    }
    __syncthreads();

    // ---- phase 4: recon + diff for both rows (thread t == d) ----
    {
        float r0 = 0.f, r1 = 0.f;
        for (int k = 0; k < Kk; k++) {
            r0 += s_sim[0][k] * keys[(size_t)s_idx[0][k] * PDd + t];
            r1 += s_sim[1][k] * keys[(size_t)s_idx[1][k] * PDd + t];
        }
        float e0 = r0 - qs[0][t];
        float e1 = r1 - qs[1][t];
        float sq = e0 * e0 + e1 * e1;
        for (int o = 32; o > 0; o >>= 1) sq += __shfl_down(sq, o);
        if ((t & 63) == 0) red[0][t >> 6] = sq;
        __syncthreads();
        if (t == 0) atomicAdd(out + OUT_LOSS,
                              (red[0][0] + red[0][1] + red[0][2] + red[0][3]) * LOSS_SCALE);
    }

    // ---- phase 5: 16 contiguous out rows (bz0*K .. bz0*K+15) = KW[idx] gather --
    float4* orow = (float4*)out + (size_t)bz0 * Kk * ED4;
    for (int i = t; i < 2 * Kk * ED4; i += 256) {
        int which = i / ED4;         // 0..15
        int e4    = i - which * ED4;
        int idx   = s_idx[which >> 3][which & 7];
        orow[i] = ((const float4*)(KW + (size_t)idx * EDd))[e4];
    }
}

extern "C" void kernel_launch(void* const* d_in, const int* in_sizes, int n_in,
                              void* d_out, int out_size, void* d_ws, size_t ws_size,
                              hipStream_t stream) {
    const float* x    = (const float*)d_in[0];   // [32, 16*197, 768]
    const float* Win  = (const float*)d_in[1];   // [256, 768]
    const float* Wout = (const float*)d_in[2];   // [768, 256]
    const float* pv   = (const float*)d_in[3];   // [64, 1, 256]
    float* out = (float*)d_out;                  // [32,128,768] ++ [1]
    float* ws  = (float*)d_ws;

    float* keys = ws;                 // 64*256 = 16384
    float* KW   = ws + 16384;         // 64*768 = 49152

    k_keys <<<SIZEk, 256, 0, stream>>>(pv, Wout, keys, KW, out);
    k_fused<<<RB + SIZEk, 256, 0, stream>>>((const float4*)x, Win, keys, KW, out);
}

// Round 5
// 471.960 us; speedup vs baseline: 1.0988x; 1.0326x over previous
//
#include <hip/hip_runtime.h>

#define Ff 16
#define Kk 8
#define SIZEk 64
#define PDd 256
#define EDd 768
#define Nn 197
#define BZz 512          // B*F
#define NPROD 64         // producer (keys/KW/ksim) blocks
#define RB  256          // route blocks (2 bz each)
#define ED4 192          // 768/4
#define PD4 64           // 256/4
#define OUT_LOSS ((size_t)32 * 128 * EDd)   // 3145728: ps_loss slot in d_out
#define LOSS_SCALE (1.0f / 32.0f)           // F/BZ = 16/512
#define MAGIC 0x5A17EC0Du                   // != 0xAAAAAAAA poison, != 0

// One kernel. Blocks 0..63 (producers): keys[s]=l2norm(pv[s]); KW[s]=keys[s]@Wout^T;
// publish slot[s]=MAGIC (release, agent scope); then ksim row s after acquiring all
// slots. Blocks 64..319 (route, 2 bz each): mean -> query run before the dependency;
// acquire all 64 slots just before top-8. Producer work hides under the ~45us HBM
// phase; expected spin time ~0. launch_bounds(256,2) => >=2 blocks/CU => all 320
// blocks co-resident => no spin deadlock.
__global__ __launch_bounds__(256, 2) void k_all(const float4* __restrict__ x,
                                                const float* __restrict__ Win,
                                                const float* __restrict__ Wout,
                                                const float* __restrict__ pv,
                                                float* __restrict__ keys,
                                                float* __restrict__ KW,
                                                unsigned* __restrict__ slots,
                                                float* __restrict__ out) {
    int blk = blockIdx.x, t = threadIdx.x;

    if (blk < NPROD) {
        // ================= producer block s =================
        __shared__ float ks[PDd];
        __shared__ float redp[4];
        __shared__ float s_norm;
        int s = blk;
        float v  = pv[(size_t)s * PDd + t];
        float sq = v * v;
        for (int o = 32; o > 0; o >>= 1) sq += __shfl_down(sq, o);
        if ((t & 63) == 0) redp[t >> 6] = sq;
        __syncthreads();
        if (t == 0) s_norm = fmaxf(sqrtf(redp[0] + redp[1] + redp[2] + redp[3]), 1e-12f);
        __syncthreads();
        float kv = v / s_norm;
        ks[t] = kv;
        keys[(size_t)s * PDd + t] = kv;
        __syncthreads();

        // KW row s: 768 outputs, 3 per thread
        for (int r = 0; r < 3; r++) {
            int e = t + 256 * r;
            const float4* w  = (const float4*)(Wout + (size_t)e * PDd);
            const float4* k4 = (const float4*)ks;
            float d = 0.f;
            for (int i = 0; i < PD4; i++) {
                float4 wv = w[i]; float4 kvv = k4[i];
                d += wv.x * kvv.x + wv.y * kvv.y + wv.z * kvv.z + wv.w * kvv.w;
            }
            KW[(size_t)s * EDd + e] = d;
        }
        if (s == 0 && t == 0) out[OUT_LOSS] = 0.0f;   // ordered before slot-0 release
        __syncthreads();   // compiler emits vmcnt(0) drain before barrier: all stores in L2
        if (t == 0)
            __hip_atomic_store(&slots[s], MAGIC, __ATOMIC_RELEASE, __HIP_MEMORY_SCOPE_AGENT);

        // ---- ksim row s (needs ALL keys) ----
        if (t < SIZEk) {
            while (__hip_atomic_load(&slots[t], __ATOMIC_ACQUIRE, __HIP_MEMORY_SCOPE_AGENT)
                   != MAGIC)
                __builtin_amdgcn_s_sleep(8);
        }
        __syncthreads();
        if (t < SIZEk) {
            const float4* a = (const float4*)(keys + (size_t)s * PDd);
            const float4* b = (const float4*)(keys + (size_t)t * PDd);
            float d = 0.f;
            for (int c = 0; c < PD4; c++) {
                float4 av = a[c], bv = b[c];
                d += av.x * bv.x + av.y * bv.y + av.z * bv.z + av.w * bv.w;
            }
            float vv = fabsf(d - (s == t ? 1.0f : 0.0f));
            for (int o = 32; o > 0; o >>= 1) vv += __shfl_down(vv, o);
            if (t == 0) atomicAdd(out + OUT_LOSS, vv * LOSS_SCALE);
        }
        return;
    }

    // ================= route block: bz pair {2b, 2b+1} =================
    __shared__ float xs[2][EDd];     // xf for both rows (as 192 float4 each)
    __shared__ float qs[2][PDd];     // normalized query rows
    __shared__ int   s_idx[2][Kk];
    __shared__ float s_sim[2][Kk];
    __shared__ float red[2][4];
    int bz0 = (blk - NPROD) * 2;

    // ---- phase 1: frame means, both rows (threads 0..191, one f4-column each) --
    if (t < ED4) {
        const float4* b0 = x + (size_t)bz0 * Nn * ED4;
        const float4* b1 = b0 + (size_t)Nn * ED4;
        float4 s0 = make_float4(0.f, 0.f, 0.f, 0.f);
        float4 s1 = make_float4(0.f, 0.f, 0.f, 0.f);
        int n = 0;
        for (; n + 4 <= Nn; n += 4) {      // 8 loads in flight per thread
            float4 a0 = b0[(n + 0) * ED4 + t];
            float4 a1 = b0[(n + 1) * ED4 + t];
            float4 a2 = b0[(n + 2) * ED4 + t];
            float4 a3 = b0[(n + 3) * ED4 + t];
            float4 c0 = b1[(n + 0) * ED4 + t];
            float4 c1 = b1[(n + 1) * ED4 + t];
            float4 c2 = b1[(n + 2) * ED4 + t];
            float4 c3 = b1[(n + 3) * ED4 + t];
            s0.x += (a0.x + a1.x) + (a2.x + a3.x);
            s0.y += (a0.y + a1.y) + (a2.y + a3.y);
            s0.z += (a0.z + a1.z) + (a2.z + a3.z);
            s0.w += (a0.w + a1.w) + (a2.w + a3.w);
            s1.x += (c0.x + c1.x) + (c2.x + c3.x);
            s1.y += (c0.y + c1.y) + (c2.y + c3.y);
            s1.z += (c0.z + c1.z) + (c2.z + c3.z);
            s1.w += (c0.w + c1.w) + (c2.w + c3.w);
        }
        for (; n < Nn; n++) {
            float4 a = b0[n * ED4 + t];
            float4 c = b1[n * ED4 + t];
            s0.x += a.x; s0.y += a.y; s0.z += a.z; s0.w += a.w;
            s1.x += c.x; s1.y += c.y; s1.z += c.z; s1.w += c.w;
        }
        const float inv = 1.0f / (float)Nn;
        s0.x *= inv; s0.y *= inv; s0.z *= inv; s0.w *= inv;
        s1.x *= inv; s1.y *= inv; s1.z *= inv; s1.w *= inv;
        ((float4*)xs[0])[t] = s0;
        ((float4*)xs[1])[t] = s1;
    }
    __syncthreads();

    // ---- phase 2: query p=t for both rows (one W_in read, two dots) ----
    {
        const float4* w  = (const float4*)Win + (size_t)t * ED4;
        const float4* x0 = (const float4*)xs[0];
        const float4* x1 = (const float4*)xs[1];
        float d0 = 0.f, d1 = 0.f;
        for (int i = 0; i < ED4; i++) {
            float4 wv = w[i];
            float4 u0 = x0[i], u1 = x1[i];
            d0 += wv.x * u0.x + wv.y * u0.y + wv.z * u0.z + wv.w * u0.w;
            d1 += wv.x * u1.x + wv.y * u1.y + wv.z * u1.z + wv.w * u1.w;
        }
        float sq0 = d0 * d0, sq1 = d1 * d1;
        for (int o = 32; o > 0; o >>= 1) {
            sq0 += __shfl_down(sq0, o);
            sq1 += __shfl_down(sq1, o);
        }
        if ((t & 63) == 0) { red[0][t >> 6] = sq0; red[1][t >> 6] = sq1; }
        __syncthreads();
        float n0 = fmaxf(sqrtf(red[0][0] + red[0][1] + red[0][2] + red[0][3]), 1e-12f);
        float n1 = fmaxf(sqrtf(red[1][0] + red[1][1] + red[1][2] + red[1][3]), 1e-12f);
        qs[0][t] = d0 / n0;
        qs[1][t] = d1 / n1;
    }

    // ---- acquire keys/KW (threads 0..63 poll one slot each; ~0 spin expected) --
    if (t < SIZEk) {
        while (__hip_atomic_load(&slots[t], __ATOMIC_ACQUIRE, __HIP_MEMORY_SCOPE_AGENT)
               != MAGIC)
            __builtin_amdgcn_s_sleep(8);
    }
    __syncthreads();

    // ---- phase 3: sim + top-8; wave 0 -> row 0, wave 1 -> row 1 ----
    if (t < 2 * SIZEk) {
        int row  = t >> 6;           // wave id
        int lane = t & 63;
        const float4* kr = (const float4*)(keys + (size_t)lane * PDd);
        const float4* qr = (const float4*)qs[row];
        float d = 0.f;
        for (int c = 0; c < PD4; c++) {
            float4 a = kr[c], b = qr[c];
            d += a.x * b.x + a.y * b.y + a.z * b.z + a.w * b.w;
        }
        float v = d;
        for (int k = 0; k < Kk; k++) {
            float mv = v; int mi = lane;
            for (int o = 32; o > 0; o >>= 1) {
                float ov = __shfl_xor(mv, o);
                int   oi = __shfl_xor(mi, o);
                if (ov > mv || (ov == mv && oi < mi)) { mv = ov; mi = oi; }
            }
            if (lane == 0) { s_idx[row][k] = mi; s_sim[row][k] = mv; }
            if (lane == mi) v = -3e38f;  // remove winner (tie -> lowest idx, like lax.top_k)
        }
    }
    __syncthreads();

    // ---- phase 4: recon + diff for both rows (thread t == d) ----
    {
        float r0 = 0.f, r1 = 0.f;
        for (int k = 0; k < Kk; k++) {
            r0 += s_sim[0][k] * keys[(size_t)s_idx[0][k] * PDd + t];
            r1 += s_sim[1][k] * keys[(size_t)s_idx[1][k] * PDd + t];
        }
        float e0 = r0 - qs[0][t];
        float e1 = r1 - qs[1][t];
        float sq = e0 * e0 + e1 * e1;
        for (int o = 32; o > 0; o >>= 1) sq += __shfl_down(sq, o);
        if ((t & 63) == 0) red[0][t >> 6] = sq;
        __syncthreads();
        if (t == 0) atomicAdd(out + OUT_LOSS,
                              (red[0][0] + red[0][1] + red[0][2] + red[0][3]) * LOSS_SCALE);
    }

    // ---- phase 5: 16 contiguous out rows (bz0*K .. bz0*K+15) = KW[idx] gather --
    float4* orow = (float4*)out + (size_t)bz0 * Kk * ED4;
    for (int i = t; i < 2 * Kk * ED4; i += 256) {
        int which = i / ED4;         // 0..15
        int e4    = i - which * ED4;
        int idx   = s_idx[which >> 3][which & 7];
        orow[i] = ((const float4*)(KW + (size_t)idx * EDd))[e4];
    }
}

extern "C" void kernel_launch(void* const* d_in, const int* in_sizes, int n_in,
                              void* d_out, int out_size, void* d_ws, size_t ws_size,
                              hipStream_t stream) {
    const float* x    = (const float*)d_in[0];   // [32, 16*197, 768]
    const float* Win  = (const float*)d_in[1];   // [256, 768]
    const float* Wout = (const float*)d_in[2];   // [768, 256]
    const float* pv   = (const float*)d_in[3];   // [64, 1, 256]
    float* out = (float*)d_out;                  // [32,128,768] ++ [1]
    float* ws  = (float*)d_ws;

    float*    keys  = ws;                        // 64*256 = 16384 floats
    float*    KW    = ws + 16384;                // 64*768 = 49152 floats
    unsigned* slots = (unsigned*)(ws + 65536);   // 64 flags (poisoned != MAGIC each launch)

    k_all<<<NPROD + RB, 256, 0, stream>>>((const float4*)x, Win, Wout, pv,
                                          keys, KW, slots, out);
}